// Round 8
// baseline (475.822 us; speedup 1.0000x reference)
//
#include <hip/hip_runtime.h>
#include <math.h>

#define NN 64
#define CC 64
#define TDIM 288
#define VV 19
#define DD 192
#define SS (TDIM*VV)        /* 5472 */
#define MSAMP (NN*SS)       /* 350208 samples for both batchnorms */

/* workspace layout (float offsets) */
#define WS_S    0           /* 64x64 second-moment sums           */
#define WS_MU   4096        /* 64 channel sums of x               */
#define WS_ZSUM 4160        /* 64 z sums                          */
#define WS_ZSS  4224        /* 64 z sum-of-squares                */
#define WS_BETA 4288        /* 192 folded bn0 shifts              */
#define WS_WP   4480        /* 64x192 folded weights W*rs0        */
#define WS_AP   16768       /* 3*8*19*19 normalized adjacency     */
#define WS_ZSC  25432       /* 64 final scale                     */
#define WS_ZSH  25496       /* 64 final shift                     */
#define WS_Z    25600       /* z tensor, 64*64*288*19 bf16 (44.8MB) */

typedef __attribute__((ext_vector_type(8))) short short8;
typedef __attribute__((ext_vector_type(4))) float f32x4;

__device__ __forceinline__ short f2bf(float f) {
    unsigned u = __float_as_uint(f);
    u = (u + 0x7FFFu + ((u >> 16) & 1u)) >> 16;     /* RNE, inputs finite */
    return (short)u;
}
__device__ __forceinline__ float bf2f(unsigned short h) {
    return __uint_as_float((unsigned)h << 16);
}

/* ---------------- K1: S = sum x x^T (bf16 MFMA), mu (f32) ----------------- */
__global__ __launch_bounds__(256, 4) void k1_cov(const float* __restrict__ x,
                                                 float* __restrict__ ws) {
    __shared__ short Xk[6144];           /* [jg=12][c=64][e=8] bf16 */
    const int tid = threadIdx.x;
    const int wv = tid >> 6, lane = tid & 63;
    const int lrow = lane & 15, lgrp = lane >> 4;
    const int cs = tid >> 2, jq = tid & 3;

    f32x4 acc[4];
#pragma unroll
    for (int ct = 0; ct < 4; ++ct)
#pragma unroll
        for (int r = 0; r < 4; ++r) acc[ct][r] = 0.f;
    float mu = 0.f;

    for (int i = 0; i < 8; ++i) {
        const int cid = blockIdx.x * 8 + i;          /* 0..3647 */
        const int nn = cid / 57;
        const int off = (cid - nn * 57) * 96;
        const float* xp = x + (size_t)nn * (CC * SS) + (size_t)cs * SS + off + jq * 24;
        __syncthreads();
#pragma unroll
        for (int u = 0; u < 6; ++u) {
            const float4 v = *(const float4*)&xp[u * 4];
            mu += (v.x + v.y) + (v.z + v.w);
            const int j = jq * 24 + u * 4;
            const int base = (j >> 3) * 512 + cs * 8 + (j & 7);
            *(unsigned*)&Xk[base]     = (unsigned)(unsigned short)f2bf(v.x) |
                                        ((unsigned)(unsigned short)f2bf(v.y) << 16);
            *(unsigned*)&Xk[base + 2] = (unsigned)(unsigned short)f2bf(v.z) |
                                        ((unsigned)(unsigned short)f2bf(v.w) << 16);
        }
        __syncthreads();
#pragma unroll
        for (int ks = 0; ks < 3; ++ks) {
            const short8 a = *(const short8*)&Xk[(ks * 4 + lgrp) * 512 + (wv * 16 + lrow) * 8];
#pragma unroll
            for (int ct = 0; ct < 4; ++ct) {
                const short8 b = *(const short8*)&Xk[(ks * 4 + lgrp) * 512 + (ct * 16 + lrow) * 8];
                acc[ct] = __builtin_amdgcn_mfma_f32_16x16x32_bf16(a, b, acc[ct], 0, 0, 0);
            }
        }
    }
    mu += __shfl_down(mu, 1);
    mu += __shfl_down(mu, 2);
    if ((tid & 3) == 0) atomicAdd(&ws[WS_MU + cs], mu);
#pragma unroll
    for (int ct = 0; ct < 4; ++ct)
#pragma unroll
        for (int r = 0; r < 4; ++r)
            atomicAdd(&ws[WS_S + (wv * 16 + lgrp * 4 + r) * 64 + ct * 16 + lrow],
                      acc[ct][r]);
}

/* -------- K2: analytic bn0 stats -> folded weights; normalized adjacency -- */
__global__ __launch_bounds__(256) void k2_prep(const float* __restrict__ A,
                                               const float* __restrict__ W,
                                               const float* __restrict__ bias,
                                               float* __restrict__ ws) {
    const int tid = threadIdx.x;
    if (blockIdx.x == 3) {
        for (int f = tid; f < 3 * 19 * 19; f += 256) {
            const int k = f / 361, vw = f % 361;
            const int v = vw / 19, w2 = vw % 19;
            float ssq = 0.f;
            for (int g = 0; g < 8; ++g) {
                const float a = A[((k * 8 + g) * 19 + v) * 19 + w2];
                ssq = fmaf(a, a, ssq);
            }
            const float inv = 1.0f / (sqrtf(8.0f * ssq) + 1e-4f);
            for (int g = 0; g < 8; ++g)
                ws[WS_AP + ((k * 8 + g) * 19 + v) * 19 + w2] =
                    A[((k * 8 + g) * 19 + v) * 19 + w2] * inv;
        }
        return;
    }
    __shared__ float Sn[64][64];
    __shared__ float mun[64];
    const float invM = 1.0f / (float)MSAMP;
    for (int f = tid; f < 4096; f += 256) Sn[f >> 6][f & 63] = ws[WS_S + f] * invM;
    if (tid < 64) mun[tid] = ws[WS_MU + tid] * invM;
    __syncthreads();
    if (tid < 64) {
        const int d = blockIdx.x * 64 + tid;
        float w[64];
#pragma unroll
        for (int c = 0; c < 64; ++c) w[c] = W[c * DD + d];
        float wmu = 0.f;
#pragma unroll
        for (int c = 0; c < 64; ++c) wmu = fmaf(w[c], mun[c], wmu);
        float q = 0.f;
#pragma unroll
        for (int c = 0; c < 64; ++c) {
            float t0 = 0.f, t1 = 0.f, t2 = 0.f, t3 = 0.f;
#pragma unroll
            for (int c2 = 0; c2 < 64; c2 += 4) {
                t0 = fmaf(Sn[c][c2 + 0], w[c2 + 0], t0);
                t1 = fmaf(Sn[c][c2 + 1], w[c2 + 1], t1);
                t2 = fmaf(Sn[c][c2 + 2], w[c2 + 2], t2);
                t3 = fmaf(Sn[c][c2 + 3], w[c2 + 3], t3);
            }
            q = fmaf(w[c], (t0 + t1) + (t2 + t3), q);
        }
        const float var = q - wmu * wmu;
        const float rs = rsqrtf(var + 1e-5f);
        ws[WS_BETA + d] = -wmu * rs;                  /* (b - (wmu+b))*rs */
#pragma unroll
        for (int c = 0; c < 64; ++c) ws[WS_WP + c * DD + d] = w[c] * rs;
    }
}

/* ---- K3: MFMA projection + MFMA adjacency contraction -> z (bf16) -------- */
/* Y2 is XOR-swizzled: logical (g,qg,m,e) at physical m' = m ^ (g&7).         */
/* z batch-stats are accumulated in-kernel (fused former k4a).                */
__global__ __launch_bounds__(256, 3) void k3_main(const float* __restrict__ x,
                                                  float* __restrict__ ws) {
    __shared__ short Xs[5120];       /* [kg=8][j=80][e=8] bf16  (10 KB) */
    __shared__ short Y2[16384];      /* [g=8][qg=8][m^g=32][e=8] bf16 (32 KB) */
    const int tid = threadIdx.x;
    const int wv = tid >> 6, lane = tid & 63;
    const int lrow = lane & 15, lgrp = lane >> 4;
    const int n = blockIdx.y;
    const int sb0 = blockIdx.x * 16 * 19;

    /* zero the q-pad of Y2 (q=57..63): same physical set under the swizzle */
    {
        const int g = tid >> 5, m = tid & 31;
        const int base = g * 2048 + 7 * 256 + m * 8;
#pragma unroll
        for (int e = 1; e < 8; ++e) Y2[base + e] = 0;
    }

    /* projection B-fragments (Wp^T) + beta, in registers */
    short8 WpB[3][2];
    float betaR[3];
#pragma unroll
    for (int nt = 0; nt < 3; ++nt) {
        const int d = (wv * 3 + nt) * 16 + lrow;
        betaR[nt] = ws[WS_BETA + d];
#pragma unroll
        for (int ks = 0; ks < 2; ++ks) {
            short8 tm;
#pragma unroll
            for (int e = 0; e < 8; ++e) {
                const int c = ks * 32 + lgrp * 8 + e;
                tm[e] = f2bf(ws[WS_WP + c * DD + d]);
            }
            WpB[nt][ks] = tm;
        }
    }
    /* contraction B-fragments (Ap) in registers; zero-padded q>=57, w>=19 */
    short8 ApB[2][2][2];
#pragma unroll
    for (int gi = 0; gi < 2; ++gi) {
        const int g = wv * 2 + gi;
#pragma unroll
        for (int nt = 0; nt < 2; ++nt) {
            const int w2 = nt * 16 + lrow;
#pragma unroll
            for (int ks = 0; ks < 2; ++ks) {
                short8 tm;
#pragma unroll
                for (int e = 0; e < 8; ++e) {
                    const int q = ks * 32 + lgrp * 8 + e;
                    short val = 0;
                    if (q < 57 && w2 < 19) {
                        const int k = q / 19, v = q - k * 19;
                        val = f2bf(ws[WS_AP + ((k * 8 + g) * 19 + v) * 19 + w2]);
                    }
                    tm[e] = val;
                }
                ApB[gi][nt][ks] = tm;
            }
        }
    }

    const float* xb = x + (size_t)n * (CC * SS);
    unsigned short* zbh = (unsigned short*)(ws + WS_Z) + (size_t)n * (CC * SS);
    const int cs = tid >> 2, jq = tid & 3;          /* staging roles */

    float zsA[2][2]  = {{0.f, 0.f}, {0.f, 0.f}};    /* [mt][gi] z-sums   */
    float zssA[2][2] = {{0.f, 0.f}, {0.f, 0.f}};    /* [mt][gi] z-sumsq  */

    for (int sc = 0; sc < 4; ++sc) {
        const int sb = sb0 + sc * 76;
        __syncthreads();
        /* stage X tile: 64ch x 76 samples -> bf16, k-octet-major */
        {
            const float* xp = xb + (size_t)cs * SS + sb + jq * 19;
            const int bi = (cs >> 3) * 640 + (cs & 7);
#pragma unroll
            for (int jj = 0; jj < 19; ++jj)
                Xs[bi + (jq * 19 + jj) * 8] = f2bf(xp[jj]);
        }
        __syncthreads();
        /* projection: y[j][d] = X * Wp + beta, scatter into swizzled Y2 */
#pragma unroll
        for (int mt = 0; mt < 5; ++mt) {
            const short8 a0 = *(const short8*)&Xs[(0 + lgrp) * 640 + (mt * 16 + lrow) * 8];
            const short8 a1 = *(const short8*)&Xs[(4 + lgrp) * 640 + (mt * 16 + lrow) * 8];
            const int j0 = mt * 16 + lgrp * 4;
#pragma unroll
            for (int nt = 0; nt < 3; ++nt) {
                f32x4 acc = {0.f, 0.f, 0.f, 0.f};
                acc = __builtin_amdgcn_mfma_f32_16x16x32_bf16(a0, WpB[nt][0], acc, 0, 0, 0);
                acc = __builtin_amdgcn_mfma_f32_16x16x32_bf16(a1, WpB[nt][1], acc, 0, 0, 0);
                const int d = (wv * 3 + nt) * 16 + lrow;
                const int k = d >> 6, c2 = d & 63;
                const int g = c2 & 7, c8 = c2 >> 3;
#pragma unroll
                for (int r = 0; r < 4; ++r) {
                    const int j = j0 + r;
                    if (j < 76) {
                        const int t = (j * 27) >> 9;       /* j/19 for j<80 */
                        const int v = j - t * 19;
                        const int q = k * 19 + v;
                        const int m = c8 * 4 + t;
                        Y2[g * 2048 + (q >> 3) * 256 + (m ^ g) * 8 + (q & 7)] =
                            f2bf(acc[r] + betaR[nt]);
                    }
                }
            }
        }
        __syncthreads();
        /* contraction: z[(c8,t)][w] = Y2_g * Ap_g, swizzled b128 A-frags */
#pragma unroll
        for (int gi = 0; gi < 2; ++gi) {
            const int g = wv * 2 + gi;
#pragma unroll
            for (int mt = 0; mt < 2; ++mt) {
                const int mrow = mt * 16 + lrow;
                const short8 a0 = *(const short8*)&Y2[g * 2048 + (0 + lgrp) * 256 + (mrow ^ g) * 8];
                const short8 a1 = *(const short8*)&Y2[g * 2048 + (4 + lgrp) * 256 + (mrow ^ g) * 8];
                f32x4 acc0 = {0.f, 0.f, 0.f, 0.f};
                f32x4 acc1 = {0.f, 0.f, 0.f, 0.f};
                acc0 = __builtin_amdgcn_mfma_f32_16x16x32_bf16(a0, ApB[gi][0][0], acc0, 0, 0, 0);
                acc0 = __builtin_amdgcn_mfma_f32_16x16x32_bf16(a1, ApB[gi][0][1], acc0, 0, 0, 0);
                acc1 = __builtin_amdgcn_mfma_f32_16x16x32_bf16(a0, ApB[gi][1][0], acc1, 0, 0, 0);
                acc1 = __builtin_amdgcn_mfma_f32_16x16x32_bf16(a1, ApB[gi][1][1], acc1, 0, 0, 0);
#pragma unroll
                for (int r = 0; r < 4; ++r) {
                    const int m = mt * 16 + lgrp * 4 + r;
                    /* channel decomposition: c2 = c8*8 + g, c8 = m>>2 */
                    const int c = (m >> 2) * 8 + g;
                    const size_t s = (size_t)c * SS + sb + (m & 3) * 19;
                    const float zv0 = acc0[r];
                    zbh[s + lrow] = (unsigned short)f2bf(zv0);
                    zsA[mt][gi] += zv0;
                    zssA[mt][gi] = fmaf(zv0, zv0, zssA[mt][gi]);
                    if (lrow < 3) {
                        const float zv1 = acc1[r];
                        zbh[s + 16 + lrow] = (unsigned short)f2bf(zv1);
                        zsA[mt][gi] += zv1;
                        zssA[mt][gi] = fmaf(zv1, zv1, zssA[mt][gi]);
                    }
                }
            }
        }
    }
    /* fused z-stat reduction: 16 lanes of a group share one channel */
#pragma unroll
    for (int mt = 0; mt < 2; ++mt)
#pragma unroll
        for (int gi = 0; gi < 2; ++gi) {
            float s = zsA[mt][gi], q = zssA[mt][gi];
            s += __shfl_xor(s, 1); q += __shfl_xor(q, 1);
            s += __shfl_xor(s, 2); q += __shfl_xor(q, 2);
            s += __shfl_xor(s, 4); q += __shfl_xor(q, 4);
            s += __shfl_xor(s, 8); q += __shfl_xor(q, 8);
            if (lrow == 0) {
                const int c = (mt * 4 + lgrp) * 8 + wv * 2 + gi;
                atomicAdd(&ws[WS_ZSUM + c], s);
                atomicAdd(&ws[WS_ZSS + c], q);
            }
        }
}

/* ---------------- K4b: finalize z batchnorm scale/shift ------------------- */
__global__ void k4b_final(float* __restrict__ ws) {
    const int c = threadIdx.x;
    if (c < 64) {
        const float invM = 1.0f / (float)MSAMP;
        const float m = ws[WS_ZSUM + c] * invM;
        const float e2 = ws[WS_ZSS + c] * invM;
        const float var = e2 - m * m;
        const float sc = 1e-6f * rsqrtf(var + 1e-5f);
        ws[WS_ZSC + c] = sc;
        ws[WS_ZSH + c] = -m * sc;
    }
}

/* ---------------- K5: out = relu(x + z*sc[c] + sh[c]), z bf16 ------------- */
__global__ __launch_bounds__(256) void k5_final(const float* __restrict__ x,
                                                const float* __restrict__ ws,
                                                float* __restrict__ out) {
    __shared__ float sc[64], sh[64];
    if (threadIdx.x < 64) {
        sc[threadIdx.x] = ws[WS_ZSC + threadIdx.x];
        sh[threadIdx.x] = ws[WS_ZSH + threadIdx.x];
    }
    __syncthreads();
    const unsigned short* zh = (const unsigned short*)(ws + WS_Z);
    const int total4 = (NN * CC * SS) / 4;
    for (int i4 = blockIdx.x * 256 + threadIdx.x; i4 < total4;
         i4 += gridDim.x * 256) {
        const int i = i4 * 4;
        const int c = (i / SS) & 63;           /* SS%4==0: uniform over 4 */
        const float4 xv = *(const float4*)&x[i];
        const ushort4 zv = *(const ushort4*)&zh[i];
        float4 o;
        o.x = fmaxf(fmaf(bf2f(zv.x), sc[c], sh[c]) + xv.x, 0.f);
        o.y = fmaxf(fmaf(bf2f(zv.y), sc[c], sh[c]) + xv.y, 0.f);
        o.z = fmaxf(fmaf(bf2f(zv.z), sc[c], sh[c]) + xv.z, 0.f);
        o.w = fmaxf(fmaf(bf2f(zv.w), sc[c], sh[c]) + xv.w, 0.f);
        *(float4*)&out[i] = o;
    }
}

extern "C" void kernel_launch(void* const* d_in, const int* in_sizes, int n_in,
                              void* d_out, int out_size, void* d_ws, size_t ws_size,
                              hipStream_t stream) {
    (void)in_sizes; (void)n_in; (void)out_size; (void)ws_size;
    const float* x    = (const float*)d_in[0];
    const float* A    = (const float*)d_in[1];
    const float* W    = (const float*)d_in[2];
    const float* bias = (const float*)d_in[3];
    float* out = (float*)d_out;
    float* ws  = (float*)d_ws;

    hipMemsetAsync(d_ws, 0, WS_BETA * sizeof(float), stream);

    k1_cov   <<<456, 256, 0, stream>>>(x, ws);
    k2_prep  <<<4,   256, 0, stream>>>(A, W, bias, ws);
    k3_main  <<<dim3(18, 64), 256, 0, stream>>>(x, ws);
    k4b_final<<<1,    64, 0, stream>>>(ws);
    k5_final <<<2048, 256, 0, stream>>>(x, ws, out);
}

// Round 10
// 289.345 us; speedup vs baseline: 1.6445x; 1.6445x over previous
//
#include <hip/hip_runtime.h>
#include <math.h>

#define NN 64
#define CC 64
#define TDIM 288
#define VV 19
#define DD 192
#define SS (TDIM*VV)        /* 5472 */
#define MSAMP (NN*SS)       /* 350208 samples for both batchnorms */

/* workspace layout (float offsets). No atomics anywhere: partials + reduce. */
#define WS_S    0           /* 64x64 second-moment (reduced by k1b)        */
#define WS_MU   4096        /* 64 channel sums of x (reduced by k1b)       */
#define WS_BETA 4288        /* 192 folded bn0 shifts                       */
#define WS_WP   4480        /* 64x192 folded weights W*rs0                 */
#define WS_AP   16768       /* 3*8*19*19 normalized adjacency              */
#define WS_ZSC  25432       /* 64 final scale                              */
#define WS_ZSH  25496       /* 64 final shift                              */
#define WS_Z    25600       /* z tensor, 64*64*288*19 bf16 (44.8 MB)       */
#define WS_SP   11232256    /* k1 S partials: 456 x 4096                   */
#define WS_MUP  13100032    /* k1 mu partials: 456 x 64                    */
#define WS_ZP   13129216    /* k3 z-stat partials: 1152 x 128              */

typedef __attribute__((ext_vector_type(8))) short short8;
typedef __attribute__((ext_vector_type(4))) float f32x4;

__device__ __forceinline__ short f2bf(float f) {
    unsigned u = __float_as_uint(f);
    u = (u + 0x7FFFu + ((u >> 16) & 1u)) >> 16;     /* RNE, inputs finite */
    return (short)u;
}
__device__ __forceinline__ float bf2f(unsigned short h) {
    return __uint_as_float((unsigned)h << 16);
}

/* ---------------- K1: S = sum x x^T (bf16 MFMA), mu (f32) ----------------- */
/* atomic-free: per-block partials to WS_SP / WS_MUP                          */
__global__ __launch_bounds__(256, 4) void k1_cov(const float* __restrict__ x,
                                                 float* __restrict__ ws) {
    __shared__ short Xk[6144];           /* [jg=12][c=64][e=8] bf16 */
    const int tid = threadIdx.x;
    const int wv = tid >> 6, lane = tid & 63;
    const int lrow = lane & 15, lgrp = lane >> 4;
    const int cs = tid >> 2, jq = tid & 3;

    f32x4 acc[4];
#pragma unroll
    for (int ct = 0; ct < 4; ++ct)
#pragma unroll
        for (int r = 0; r < 4; ++r) acc[ct][r] = 0.f;
    float mu = 0.f;

    for (int i = 0; i < 8; ++i) {
        const int cid = blockIdx.x * 8 + i;          /* 0..3647 */
        const int nn = cid / 57;
        const int off = (cid - nn * 57) * 96;
        const float* xp = x + (size_t)nn * (CC * SS) + (size_t)cs * SS + off + jq * 24;
        __syncthreads();
#pragma unroll
        for (int u = 0; u < 6; ++u) {
            const float4 v = *(const float4*)&xp[u * 4];
            mu += (v.x + v.y) + (v.z + v.w);
            const int j = jq * 24 + u * 4;
            const int base = (j >> 3) * 512 + cs * 8 + (j & 7);
            *(unsigned*)&Xk[base]     = (unsigned)(unsigned short)f2bf(v.x) |
                                        ((unsigned)(unsigned short)f2bf(v.y) << 16);
            *(unsigned*)&Xk[base + 2] = (unsigned)(unsigned short)f2bf(v.z) |
                                        ((unsigned)(unsigned short)f2bf(v.w) << 16);
        }
        __syncthreads();
#pragma unroll
        for (int ks = 0; ks < 3; ++ks) {
            const short8 a = *(const short8*)&Xk[(ks * 4 + lgrp) * 512 + (wv * 16 + lrow) * 8];
#pragma unroll
            for (int ct = 0; ct < 4; ++ct) {
                const short8 b = *(const short8*)&Xk[(ks * 4 + lgrp) * 512 + (ct * 16 + lrow) * 8];
                acc[ct] = __builtin_amdgcn_mfma_f32_16x16x32_bf16(a, b, acc[ct], 0, 0, 0);
            }
        }
    }
    mu += __shfl_down(mu, 1);
    mu += __shfl_down(mu, 2);
    if ((tid & 3) == 0) ws[WS_MUP + blockIdx.x * 64 + cs] = mu;
#pragma unroll
    for (int ct = 0; ct < 4; ++ct)
#pragma unroll
        for (int r = 0; r < 4; ++r)
            ws[WS_SP + blockIdx.x * 4096 +
               (wv * 16 + lgrp * 4 + r) * 64 + ct * 16 + lrow] = acc[ct][r];
}

/* ---------------- K1b: reduce k1 partials (no atomics) -------------------- */
__global__ __launch_bounds__(256) void k1b_red(float* __restrict__ ws) {
    const int tid = threadIdx.x;
    if (blockIdx.x < 16) {
        const int e = blockIdx.x * 256 + tid;
        float s = 0.f;
        for (int b = 0; b < 456; ++b) s += ws[WS_SP + b * 4096 + e];
        ws[WS_S + e] = s;
    } else if (tid < 64) {
        float s = 0.f;
        for (int b = 0; b < 456; ++b) s += ws[WS_MUP + b * 64 + tid];
        ws[WS_MU + tid] = s;
    }
}

/* -------- K2: analytic bn0 stats -> folded weights; normalized adjacency -- */
__global__ __launch_bounds__(256) void k2_prep(const float* __restrict__ A,
                                               const float* __restrict__ W,
                                               const float* __restrict__ bias,
                                               float* __restrict__ ws) {
    const int tid = threadIdx.x;
    if (blockIdx.x == 3) {
        for (int f = tid; f < 3 * 19 * 19; f += 256) {
            const int k = f / 361, vw = f % 361;
            const int v = vw / 19, w2 = vw % 19;
            float ssq = 0.f;
            for (int g = 0; g < 8; ++g) {
                const float a = A[((k * 8 + g) * 19 + v) * 19 + w2];
                ssq = fmaf(a, a, ssq);
            }
            const float inv = 1.0f / (sqrtf(8.0f * ssq) + 1e-4f);
            for (int g = 0; g < 8; ++g)
                ws[WS_AP + ((k * 8 + g) * 19 + v) * 19 + w2] =
                    A[((k * 8 + g) * 19 + v) * 19 + w2] * inv;
        }
        return;
    }
    __shared__ float Sn[64][64];
    __shared__ float mun[64];
    const float invM = 1.0f / (float)MSAMP;
    for (int f = tid; f < 4096; f += 256) Sn[f >> 6][f & 63] = ws[WS_S + f] * invM;
    if (tid < 64) mun[tid] = ws[WS_MU + tid] * invM;
    __syncthreads();
    if (tid < 64) {
        const int d = blockIdx.x * 64 + tid;
        float w[64];
#pragma unroll
        for (int c = 0; c < 64; ++c) w[c] = W[c * DD + d];
        float wmu = 0.f;
#pragma unroll
        for (int c = 0; c < 64; ++c) wmu = fmaf(w[c], mun[c], wmu);
        float q = 0.f;
#pragma unroll
        for (int c = 0; c < 64; ++c) {
            float t0 = 0.f, t1 = 0.f, t2 = 0.f, t3 = 0.f;
#pragma unroll
            for (int c2 = 0; c2 < 64; c2 += 4) {
                t0 = fmaf(Sn[c][c2 + 0], w[c2 + 0], t0);
                t1 = fmaf(Sn[c][c2 + 1], w[c2 + 1], t1);
                t2 = fmaf(Sn[c][c2 + 2], w[c2 + 2], t2);
                t3 = fmaf(Sn[c][c2 + 3], w[c2 + 3], t3);
            }
            q = fmaf(w[c], (t0 + t1) + (t2 + t3), q);
        }
        const float var = q - wmu * wmu;
        const float rs = rsqrtf(var + 1e-5f);
        ws[WS_BETA + d] = -wmu * rs;                  /* (b - (wmu+b))*rs */
#pragma unroll
        for (int c = 0; c < 64; ++c) ws[WS_WP + c * DD + d] = w[c] * rs;
    }
}

/* ---- K3: MFMA projection + MFMA adjacency contraction -> z (bf16) -------- */
/* Y2 XOR-swizzled (m' = m ^ g). z-stats -> per-block partials (no atomics). */
__global__ __launch_bounds__(256, 3) void k3_main(const float* __restrict__ x,
                                                  float* __restrict__ ws) {
    __shared__ short Xs[5120];       /* [kg=8][j=80][e=8] bf16  (10 KB) */
    __shared__ short Y2[16384];      /* [g=8][qg=8][m^g=32][e=8] bf16 (32 KB) */
    __shared__ float Zr[128];
    const int tid = threadIdx.x;
    const int wv = tid >> 6, lane = tid & 63;
    const int lrow = lane & 15, lgrp = lane >> 4;
    const int n = blockIdx.y;
    const int sb0 = blockIdx.x * 16 * 19;

    /* zero the q-pad of Y2 (q=57..63): same physical set under the swizzle */
    {
        const int g = tid >> 5, m = tid & 31;
        const int base = g * 2048 + 7 * 256 + m * 8;
#pragma unroll
        for (int e = 1; e < 8; ++e) Y2[base + e] = 0;
    }

    /* projection B-fragments (Wp^T) + beta, in registers */
    short8 WpB[3][2];
    float betaR[3];
#pragma unroll
    for (int nt = 0; nt < 3; ++nt) {
        const int d = (wv * 3 + nt) * 16 + lrow;
        betaR[nt] = ws[WS_BETA + d];
#pragma unroll
        for (int ks = 0; ks < 2; ++ks) {
            short8 tm;
#pragma unroll
            for (int e = 0; e < 8; ++e) {
                const int c = ks * 32 + lgrp * 8 + e;
                tm[e] = f2bf(ws[WS_WP + c * DD + d]);
            }
            WpB[nt][ks] = tm;
        }
    }
    /* contraction B-fragments (Ap) in registers; zero-padded q>=57, w>=19 */
    short8 ApB[2][2][2];
#pragma unroll
    for (int gi = 0; gi < 2; ++gi) {
        const int g = wv * 2 + gi;
#pragma unroll
        for (int nt = 0; nt < 2; ++nt) {
            const int w2 = nt * 16 + lrow;
#pragma unroll
            for (int ks = 0; ks < 2; ++ks) {
                short8 tm;
#pragma unroll
                for (int e = 0; e < 8; ++e) {
                    const int q = ks * 32 + lgrp * 8 + e;
                    short val = 0;
                    if (q < 57 && w2 < 19) {
                        const int k = q / 19, v = q - k * 19;
                        val = f2bf(ws[WS_AP + ((k * 8 + g) * 19 + v) * 19 + w2]);
                    }
                    tm[e] = val;
                }
                ApB[gi][nt][ks] = tm;
            }
        }
    }

    const float* xb = x + (size_t)n * (CC * SS);
    unsigned short* zbh = (unsigned short*)(ws + WS_Z) + (size_t)n * (CC * SS);
    const int cs = tid >> 2, jq = tid & 3;          /* staging roles */

    float zsA[2][2]  = {{0.f, 0.f}, {0.f, 0.f}};    /* [mt][gi] z-sums   */
    float zssA[2][2] = {{0.f, 0.f}, {0.f, 0.f}};    /* [mt][gi] z-sumsq  */

    for (int sc = 0; sc < 4; ++sc) {
        const int sb = sb0 + sc * 76;
        __syncthreads();
        /* stage X tile: 64ch x 76 samples -> bf16, k-octet-major */
        {
            const float* xp = xb + (size_t)cs * SS + sb + jq * 19;
            const int bi = (cs >> 3) * 640 + (cs & 7);
#pragma unroll
            for (int jj = 0; jj < 19; ++jj)
                Xs[bi + (jq * 19 + jj) * 8] = f2bf(xp[jj]);
        }
        __syncthreads();
        /* projection: y[j][d] = X * Wp + beta, scatter into swizzled Y2 */
#pragma unroll
        for (int mt = 0; mt < 5; ++mt) {
            const short8 a0 = *(const short8*)&Xs[(0 + lgrp) * 640 + (mt * 16 + lrow) * 8];
            const short8 a1 = *(const short8*)&Xs[(4 + lgrp) * 640 + (mt * 16 + lrow) * 8];
            const int j0 = mt * 16 + lgrp * 4;
#pragma unroll
            for (int nt = 0; nt < 3; ++nt) {
                f32x4 acc = {0.f, 0.f, 0.f, 0.f};
                acc = __builtin_amdgcn_mfma_f32_16x16x32_bf16(a0, WpB[nt][0], acc, 0, 0, 0);
                acc = __builtin_amdgcn_mfma_f32_16x16x32_bf16(a1, WpB[nt][1], acc, 0, 0, 0);
                const int d = (wv * 3 + nt) * 16 + lrow;
                const int k = d >> 6, c2 = d & 63;
                const int g = c2 & 7, c8 = c2 >> 3;
#pragma unroll
                for (int r = 0; r < 4; ++r) {
                    const int j = j0 + r;
                    if (j < 76) {
                        const int t = (j * 27) >> 9;       /* j/19 for j<80 */
                        const int v = j - t * 19;
                        const int q = k * 19 + v;
                        const int m = c8 * 4 + t;
                        Y2[g * 2048 + (q >> 3) * 256 + (m ^ g) * 8 + (q & 7)] =
                            f2bf(acc[r] + betaR[nt]);
                    }
                }
            }
        }
        __syncthreads();
        /* contraction: z[(c8,t)][w] = Y2_g * Ap_g, swizzled b128 A-frags */
#pragma unroll
        for (int gi = 0; gi < 2; ++gi) {
            const int g = wv * 2 + gi;
#pragma unroll
            for (int mt = 0; mt < 2; ++mt) {
                const int mrow = mt * 16 + lrow;
                const short8 a0 = *(const short8*)&Y2[g * 2048 + (0 + lgrp) * 256 + (mrow ^ g) * 8];
                const short8 a1 = *(const short8*)&Y2[g * 2048 + (4 + lgrp) * 256 + (mrow ^ g) * 8];
                f32x4 acc0 = {0.f, 0.f, 0.f, 0.f};
                f32x4 acc1 = {0.f, 0.f, 0.f, 0.f};
                acc0 = __builtin_amdgcn_mfma_f32_16x16x32_bf16(a0, ApB[gi][0][0], acc0, 0, 0, 0);
                acc0 = __builtin_amdgcn_mfma_f32_16x16x32_bf16(a1, ApB[gi][0][1], acc0, 0, 0, 0);
                acc1 = __builtin_amdgcn_mfma_f32_16x16x32_bf16(a0, ApB[gi][1][0], acc1, 0, 0, 0);
                acc1 = __builtin_amdgcn_mfma_f32_16x16x32_bf16(a1, ApB[gi][1][1], acc1, 0, 0, 0);
#pragma unroll
                for (int r = 0; r < 4; ++r) {
                    const int m = mt * 16 + lgrp * 4 + r;
                    /* channel decomposition: c2 = c8*8 + g, c8 = m>>2 */
                    const int c = (m >> 2) * 8 + g;
                    const size_t s = (size_t)c * SS + sb + (m & 3) * 19;
                    const float zv0 = acc0[r];
                    zbh[s + lrow] = (unsigned short)f2bf(zv0);
                    zsA[mt][gi] += zv0;
                    zssA[mt][gi] = fmaf(zv0, zv0, zssA[mt][gi]);
                    if (lrow < 3) {
                        const float zv1 = acc1[r];
                        zbh[s + 16 + lrow] = (unsigned short)f2bf(zv1);
                        zsA[mt][gi] += zv1;
                        zssA[mt][gi] = fmaf(zv1, zv1, zssA[mt][gi]);
                    }
                }
            }
        }
    }
    /* z-stat partials: 16-lane reduce -> LDS gather -> coalesced store */
#pragma unroll
    for (int mt = 0; mt < 2; ++mt)
#pragma unroll
        for (int gi = 0; gi < 2; ++gi) {
            float s = zsA[mt][gi], q = zssA[mt][gi];
            s += __shfl_xor(s, 1); q += __shfl_xor(q, 1);
            s += __shfl_xor(s, 2); q += __shfl_xor(q, 2);
            s += __shfl_xor(s, 4); q += __shfl_xor(q, 4);
            s += __shfl_xor(s, 8); q += __shfl_xor(q, 8);
            if (lrow == 0) {
                const int c = (mt * 4 + lgrp) * 8 + wv * 2 + gi;
                Zr[c] = s;
                Zr[64 + c] = q;
            }
        }
    __syncthreads();
    if (tid < 128) {
        const int bid = n * 18 + blockIdx.x;
        ws[WS_ZP + bid * 128 + tid] = Zr[tid];
    }
}

/* ------- K4b: reduce z-stat partials, finalize scale/shift (64 blocks) ---- */
__global__ __launch_bounds__(256) void k4b_final(float* __restrict__ ws) {
    const int c = blockIdx.x;
    const int tid = threadIdx.x;
    float s = 0.f, q = 0.f;
    for (int b = tid; b < 1152; b += 256) {
        s += ws[WS_ZP + b * 128 + c];
        q += ws[WS_ZP + b * 128 + 64 + c];
    }
#pragma unroll
    for (int o = 32; o; o >>= 1) { s += __shfl_down(s, o); q += __shfl_down(q, o); }
    __shared__ float rs[4], rq[4];
    if ((tid & 63) == 0) { rs[tid >> 6] = s; rq[tid >> 6] = q; }
    __syncthreads();
    if (tid == 0) {
        s = (rs[0] + rs[1]) + (rs[2] + rs[3]);
        q = (rq[0] + rq[1]) + (rq[2] + rq[3]);
        const float invM = 1.0f / (float)MSAMP;
        const float m = s * invM;
        const float var = q * invM - m * m;
        const float sc = 1e-6f * rsqrtf(var + 1e-5f);
        ws[WS_ZSC + c] = sc;
        ws[WS_ZSH + c] = -m * sc;
    }
}

/* ---------------- K5: out = relu(x + z*sc[c] + sh[c]), z bf16 ------------- */
__global__ __launch_bounds__(256) void k5_final(const float* __restrict__ x,
                                                const float* __restrict__ ws,
                                                float* __restrict__ out) {
    __shared__ float sc[64], sh[64];
    if (threadIdx.x < 64) {
        sc[threadIdx.x] = ws[WS_ZSC + threadIdx.x];
        sh[threadIdx.x] = ws[WS_ZSH + threadIdx.x];
    }
    __syncthreads();
    const unsigned short* zh = (const unsigned short*)(ws + WS_Z);
    const int total4 = (NN * CC * SS) / 4;
    for (int i4 = blockIdx.x * 256 + threadIdx.x; i4 < total4;
         i4 += gridDim.x * 256) {
        const int i = i4 * 4;
        const int c = (i / SS) & 63;           /* SS%4==0: uniform over 4 */
        const float4 xv = *(const float4*)&x[i];
        const ushort4 zv = *(const ushort4*)&zh[i];
        float4 o;
        o.x = fmaxf(fmaf(bf2f(zv.x), sc[c], sh[c]) + xv.x, 0.f);
        o.y = fmaxf(fmaf(bf2f(zv.y), sc[c], sh[c]) + xv.y, 0.f);
        o.z = fmaxf(fmaf(bf2f(zv.z), sc[c], sh[c]) + xv.z, 0.f);
        o.w = fmaxf(fmaf(bf2f(zv.w), sc[c], sh[c]) + xv.w, 0.f);
        *(float4*)&out[i] = o;
    }
}

extern "C" void kernel_launch(void* const* d_in, const int* in_sizes, int n_in,
                              void* d_out, int out_size, void* d_ws, size_t ws_size,
                              hipStream_t stream) {
    (void)in_sizes; (void)n_in; (void)out_size; (void)ws_size;
    const float* x    = (const float*)d_in[0];
    const float* A    = (const float*)d_in[1];
    const float* W    = (const float*)d_in[2];
    const float* bias = (const float*)d_in[3];
    float* out = (float*)d_out;
    float* ws  = (float*)d_ws;

    k1_cov   <<<456, 256, 0, stream>>>(x, ws);
    k1b_red  <<<17,  256, 0, stream>>>(ws);
    k2_prep  <<<4,   256, 0, stream>>>(A, W, bias, ws);
    k3_main  <<<dim3(18, 64), 256, 0, stream>>>(x, ws);
    k4b_final<<<64,  256, 0, stream>>>(ws);
    k5_final <<<2048, 256, 0, stream>>>(x, ws, out);
}